// Round 15
// baseline (371.710 us; speedup 1.0000x reference)
//
#include <hip/hip_runtime.h>
#include <math.h>

// ---------------------------------------------------------------------------
// GraphSAGE fraud detector. CSR-gather aggregation + bf16 MFMA GEMMs.
// R15: GEMM K-loop with manual-waitcnt pipelining, ALL waves computing.
// The __syncthreads in R10/R12/R14 drains vmcnt(0) every iter -> prefetch
// depth capped at 1 -> ~900 cyc exposed DMA latency/iter (1053 cyc/iter vs
// 155 cyc MFMA). Now: 4 LDS slots, depth-2 prefetch; each iter every wave
// issues tile i+2's 4 DMAs, waits s_waitcnt vmcnt(8) (its own oldest tile
// only — never 0), then raw s_barrier (asm volatile + memory clobber, so
// the compiler can't re-order LDS ops across it). Unlike R13 (producer/
// consumer, halved MFMA issue) all 4 waves compute. Slot safety: write
// slot (i+2)%4 vs slowest concurrent reader (i-1)%4 -> distance 3, 3%4!=0;
// barrier bounds wave skew to one iteration. Tail: re-issue last tile so
// vmcnt arithmetic stays uniform (R13 trick). LDS 64 KB -> 2 blocks/CU
// (R10's measured average residency was ~1.9 blocks, so little loss).
// Falsifier: if the backend inserts its own vmcnt(0) drains, this is
// neutral and the HIP-level structure space is exhausted.
// MFMA 16x16x32 bf16: A-frag A[m=lane&15][k=quad*8+j]; C/D col=lane&15,
// row=quad*4+reg (m89/m97-verified layouts).
// ---------------------------------------------------------------------------

typedef __attribute__((ext_vector_type(8))) short bf16x8;   // 8 bf16, 4 VGPRs
typedef __attribute__((ext_vector_type(4))) float f32x4;

static inline int ceil_div(int a, int b) { return (a + b - 1) / b; }

__device__ inline float bf2f_lo(unsigned u) { return __builtin_bit_cast(float, u << 16); }
__device__ inline float bf2f_hi(unsigned u) { return __builtin_bit_cast(float, u & 0xffff0000u); }
__device__ inline unsigned f2bf(float f) {   // RNE round to bf16, bits in low 16
    unsigned u = __builtin_bit_cast(unsigned, f);
    u += 0x7fffu + ((u >> 16) & 1u);
    return u >> 16;
}

// async global->LDS, 16 B per lane; LDS dest = wave-uniform base + lane*16
#define GLOAD_LDS16(gp, lp)                                                   \
    __builtin_amdgcn_global_load_lds(                                         \
        (__attribute__((address_space(1))) void*)(gp),                        \
        (__attribute__((address_space(3))) void*)(lp), 16, 0, 0)

// s_waitcnt imm (gfx9): vmcnt[3:0]+[15:14], expcnt[6:4], lgkmcnt[11:8]
// vmcnt(8), expcnt=7 (no wait), lgkmcnt=0xF (no wait):
#define WAITCNT_VM8 0x0F78

// ---------------- fused cvt(x,W1,W2) + deg histogram ----------------

__global__ void cvt3_hist_kernel(const float* __restrict__ a, unsigned short* __restrict__ ao, int na4,
                                 const float* __restrict__ b, unsigned short* __restrict__ bo, int nb4,
                                 const float* __restrict__ c, unsigned short* __restrict__ co, int nc4,
                                 const int* __restrict__ dst, int* __restrict__ deg, int E,
                                 int cvt_blocks) {
    if ((int)blockIdx.x < cvt_blocks) {
        int i = blockIdx.x * 256 + threadIdx.x;
        const float* in; unsigned short* out; int k;
        if (i < na4)                  { in = a; out = ao; k = i; }
        else if (i < na4 + nb4)       { in = b; out = bo; k = i - na4; }
        else if (i < na4 + nb4 + nc4) { in = c; out = co; k = i - na4 - nb4; }
        else return;
        float4 v = ((const float4*)in)[k];
        ushort4 o;
        o.x = (unsigned short)f2bf(v.x);
        o.y = (unsigned short)f2bf(v.y);
        o.z = (unsigned short)f2bf(v.z);
        o.w = (unsigned short)f2bf(v.w);
        ((ushort4*)out)[k] = o;
    } else {
        int e = (blockIdx.x - cvt_blocks) * 256 + threadIdx.x;
        if (e < E) atomicAdd(&deg[dst[e]], 1);
    }
}

// ---------------- CSR build ----------------

// per-1024-chunk sums
__global__ __launch_bounds__(256) void chunk_reduce(const int* __restrict__ deg,
                                                    int* __restrict__ partial, int N) {
    int base = blockIdx.x * 1024;
    int s = 0;
    for (int i = threadIdx.x; i < 1024; i += 256) {
        int idx = base + i;
        if (idx < N) s += deg[idx];
    }
    #pragma unroll
    for (int off = 32; off; off >>= 1) s += __shfl_down(s, off);
    __shared__ int ws[4];
    if ((threadIdx.x & 63) == 0) ws[threadIdx.x >> 6] = s;
    __syncthreads();
    if (threadIdx.x == 0) partial[blockIdx.x] = ws[0] + ws[1] + ws[2] + ws[3];
}

// exclusive scan of P<=64 partials (one wave); writes rowstart[N]=total
__global__ void partial_scan(int* __restrict__ partial, int* __restrict__ rowstartN, int P) {
    int lane = threadIdx.x;
    int v = (lane < P) ? partial[lane] : 0;
    int incl = v;
    #pragma unroll
    for (int off = 1; off < 64; off <<= 1) {
        int t = __shfl_up(incl, off);
        if (lane >= off) incl += t;
    }
    if (lane < P) partial[lane] = incl - v;
    if (lane == 63) *rowstartN = incl;
}

// per-chunk exclusive scan + global offset; writes rowstart and cursor
__global__ __launch_bounds__(256) void chunk_scan(const int* __restrict__ deg,
                                                  const int* __restrict__ partial,
                                                  int* __restrict__ rowstart,
                                                  int* __restrict__ cursor, int N) {
    int base = blockIdx.x * 1024 + threadIdx.x * 4;
    int v[4];
    #pragma unroll
    for (int j = 0; j < 4; ++j) {
        int i = base + j;
        v[j] = (i < N) ? deg[i] : 0;
    }
    int mysum = v[0] + v[1] + v[2] + v[3];
    int incl = mysum;
    int lane = threadIdx.x & 63, wave = threadIdx.x >> 6;
    #pragma unroll
    for (int off = 1; off < 64; off <<= 1) {
        int t = __shfl_up(incl, off);
        if (lane >= off) incl += t;
    }
    __shared__ int ws[4];
    if (lane == 63) ws[wave] = incl;
    __syncthreads();
    int run = partial[blockIdx.x] + incl - mysum;
    for (int w = 0; w < wave; ++w) run += ws[w];
    #pragma unroll
    for (int j = 0; j < 4; ++j) {
        int i = base + j;
        if (i < N) { rowstart[i] = run; cursor[i] = run; }
        run += v[j];
    }
}

__global__ void bucket_kernel(const int* __restrict__ src, const int* __restrict__ dst,
                              int* __restrict__ cursor, int* __restrict__ ebuf, int E) {
    int e = blockIdx.x * 256 + threadIdx.x;
    if (e < E) {
        int pos = atomicAdd(&cursor[dst[e]], 1);
        ebuf[pos] = src[e];
    }
}

// ---------------- gather means ----------------

// one wave per dst row; bf16 xb [N,128] -> bf16 mean [N,128]; fp32 accum
__global__ void gather_mean_128(const int* __restrict__ rowstart, const int* __restrict__ ebuf,
                                const unsigned* __restrict__ featb, unsigned* __restrict__ outb, int N) {
    int w = (blockIdx.x * blockDim.x + threadIdx.x) >> 6;
    int lane = threadIdx.x & 63;
    if (w >= N) return;
    int e0 = rowstart[w], e1 = rowstart[w + 1];
    float ax = 0.0f, ay = 0.0f;
    int i = e0;
    for (; i + 8 <= e1; i += 8) {           // 8-edge unroll for MLP
        unsigned v0 = featb[(size_t)ebuf[i]     * 64 + lane];
        unsigned v1 = featb[(size_t)ebuf[i + 1] * 64 + lane];
        unsigned v2 = featb[(size_t)ebuf[i + 2] * 64 + lane];
        unsigned v3 = featb[(size_t)ebuf[i + 3] * 64 + lane];
        unsigned v4 = featb[(size_t)ebuf[i + 4] * 64 + lane];
        unsigned v5 = featb[(size_t)ebuf[i + 5] * 64 + lane];
        unsigned v6 = featb[(size_t)ebuf[i + 6] * 64 + lane];
        unsigned v7 = featb[(size_t)ebuf[i + 7] * 64 + lane];
        ax += bf2f_lo(v0) + bf2f_lo(v1) + bf2f_lo(v2) + bf2f_lo(v3)
            + bf2f_lo(v4) + bf2f_lo(v5) + bf2f_lo(v6) + bf2f_lo(v7);
        ay += bf2f_hi(v0) + bf2f_hi(v1) + bf2f_hi(v2) + bf2f_hi(v3)
            + bf2f_hi(v4) + bf2f_hi(v5) + bf2f_hi(v6) + bf2f_hi(v7);
    }
    for (; i < e1; ++i) {
        unsigned v = featb[(size_t)ebuf[i] * 64 + lane];
        ax += bf2f_lo(v); ay += bf2f_hi(v);
    }
    float inv = 1.0f / fmaxf((float)(e1 - e0), 1.0f);
    outb[(size_t)w * 64 + lane] = f2bf(ax * inv) | (f2bf(ay * inv) << 16);
}

// one wave per dst row; bf16 feat [N,512] -> bf16 mean [N,512]; fp32 accum
__global__ void gather_mean_512(const int* __restrict__ rowstart, const int* __restrict__ ebuf,
                                const unsigned short* __restrict__ featb,
                                unsigned short* __restrict__ outb, int N) {
    int w = (blockIdx.x * blockDim.x + threadIdx.x) >> 6;
    int lane = threadIdx.x & 63;
    if (w >= N) return;
    int e0 = rowstart[w], e1 = rowstart[w + 1];
    float a[8] = {0, 0, 0, 0, 0, 0, 0, 0};
    const uint4* base = (const uint4*)featb;     // 512 bf16/row = 64 uint4/row
    int i = e0;
    for (; i + 8 <= e1; i += 8) {           // 8-edge unroll for MLP
        uint4 v0 = base[(size_t)ebuf[i]     * 64 + lane];
        uint4 v1 = base[(size_t)ebuf[i + 1] * 64 + lane];
        uint4 v2 = base[(size_t)ebuf[i + 2] * 64 + lane];
        uint4 v3 = base[(size_t)ebuf[i + 3] * 64 + lane];
        uint4 v4 = base[(size_t)ebuf[i + 4] * 64 + lane];
        uint4 v5 = base[(size_t)ebuf[i + 5] * 64 + lane];
        uint4 v6 = base[(size_t)ebuf[i + 6] * 64 + lane];
        uint4 v7 = base[(size_t)ebuf[i + 7] * 64 + lane];
        a[0] += bf2f_lo(v0.x) + bf2f_lo(v1.x) + bf2f_lo(v2.x) + bf2f_lo(v3.x)
              + bf2f_lo(v4.x) + bf2f_lo(v5.x) + bf2f_lo(v6.x) + bf2f_lo(v7.x);
        a[1] += bf2f_hi(v0.x) + bf2f_hi(v1.x) + bf2f_hi(v2.x) + bf2f_hi(v3.x)
              + bf2f_hi(v4.x) + bf2f_hi(v5.x) + bf2f_hi(v6.x) + bf2f_hi(v7.x);
        a[2] += bf2f_lo(v0.y) + bf2f_lo(v1.y) + bf2f_lo(v2.y) + bf2f_lo(v3.y)
              + bf2f_lo(v4.y) + bf2f_lo(v5.y) + bf2f_lo(v6.y) + bf2f_lo(v7.y);
        a[3] += bf2f_hi(v0.y) + bf2f_hi(v1.y) + bf2f_hi(v2.y) + bf2f_hi(v3.y)
              + bf2f_hi(v4.y) + bf2f_hi(v5.y) + bf2f_hi(v6.y) + bf2f_hi(v7.y);
        a[4] += bf2f_lo(v0.z) + bf2f_lo(v1.z) + bf2f_lo(v2.z) + bf2f_lo(v3.z)
              + bf2f_lo(v4.z) + bf2f_lo(v5.z) + bf2f_lo(v6.z) + bf2f_lo(v7.z);
        a[5] += bf2f_hi(v0.z) + bf2f_hi(v1.z) + bf2f_hi(v2.z) + bf2f_hi(v3.z)
              + bf2f_hi(v4.z) + bf2f_hi(v5.z) + bf2f_hi(v6.z) + bf2f_hi(v7.z);
        a[6] += bf2f_lo(v0.w) + bf2f_lo(v1.w) + bf2f_lo(v2.w) + bf2f_lo(v3.w)
              + bf2f_lo(v4.w) + bf2f_lo(v5.w) + bf2f_lo(v6.w) + bf2f_lo(v7.w);
        a[7] += bf2f_hi(v0.w) + bf2f_hi(v1.w) + bf2f_hi(v2.w) + bf2f_hi(v3.w)
              + bf2f_hi(v4.w) + bf2f_hi(v5.w) + bf2f_hi(v6.w) + bf2f_hi(v7.w);
    }
    for (; i < e1; ++i) {
        uint4 v = base[(size_t)ebuf[i] * 64 + lane];
        a[0] += bf2f_lo(v.x); a[1] += bf2f_hi(v.x);
        a[2] += bf2f_lo(v.y); a[3] += bf2f_hi(v.y);
        a[4] += bf2f_lo(v.z); a[5] += bf2f_hi(v.z);
        a[6] += bf2f_lo(v.w); a[7] += bf2f_hi(v.w);
    }
    float inv = 1.0f / fmaxf((float)(e1 - e0), 1.0f);
    uint4 o;
    o.x = f2bf(a[0] * inv) | (f2bf(a[1] * inv) << 16);
    o.y = f2bf(a[2] * inv) | (f2bf(a[3] * inv) << 16);
    o.z = f2bf(a[4] * inv) | (f2bf(a[5] * inv) << 16);
    o.w = f2bf(a[6] * inv) | (f2bf(a[7] * inv) << 16);
    ((uint4*)outb)[(size_t)w * 64 + lane] = o;
}

// ---------------- bf16 MFMA GEMM (4-slot manual-waitcnt pipeline) ----------
// C = relu([A0b | A1b] @ Wb^T + b)
// mode 0: store C as bf16 to outb [N, C]
// mode 1: logit[row] += sum_col C[row,col] * Wo[col]
// 1D grid, id -> xcd=id&7, col=(id>>3)&3, row=(id>>5)*8+xcd (A L2-resident,
// R10: FETCH 202->58 MB). Block 256 thr = 4 waves (2x2); tile 128x128;
// wave tile 64x64 (4x4 mfma); BK=32. 4 LDS slots, depth-2 prefetch,
// per-wave s_waitcnt vmcnt(8) + raw s_barrier. All 4 waves issue DMA and
// compute (each issues exactly 4 GLOAD_LDS16 per tile, in program order,
// so vmcnt(8) == "my oldest tile's 4 loads done").
// REQUIRES K0 == K1 (multiples of 32), C == 512.
__global__ __launch_bounds__(256) void gemm_mfma(
    const unsigned short* __restrict__ A0,   // [N, K0] bf16
    const unsigned short* __restrict__ A1,   // [N, K1] bf16, K1 == K0
    const unsigned short* __restrict__ W,    // [C, K0+K1] bf16 row-major
    const float* __restrict__ b,             // [C] fp32
    unsigned short* __restrict__ outb,       // [N, C] bf16 (mode 0)
    const float* __restrict__ Wo,            // [C] fp32    (mode 1)
    float* __restrict__ logit,               // [N] fp32    (mode 1)
    int N, int K0, int K1, int C, int mode)
{
    // --- XCD-aware decode ---
    const int nrow = (N + 127) >> 7;
    const int id   = blockIdx.x;
    const int rowb = ((id >> 5) << 3) + (id & 7);   // rslot*8 + xcd
    const int colb = (id >> 3) & 3;
    if (rowb >= nrow) return;

    const int K = K0 + K1;
    const int S = K0;               // row stride of both A0 and A1
    __shared__ short As[4][4096];   // [128][32] per slot, 8 KB; 4 slots
    __shared__ short Bs[4][4096];

    const int tid  = threadIdx.x;
    const int lane = tid & 63;
    const int wave = tid >> 6;
    const int wm = wave & 1, wn = wave >> 1;
    const int cl = lane & 15, quad = lane >> 4;
    const int row0 = rowb * 128;
    const int col0 = colb * 128;

    // staging: lane = 4r+j; wave w, load i covers tile rows w*32+i*16 .. +16
    const int r = lane >> 2;        // 0..15
    const int j = lane & 3;         // 16B chunk within the row's 64B K-slice
    const int trow0 = wave * 32 + r;
    const int trow1 = trow0 + 16;
    // clamp OOB tile rows to N-1 (loaded garbage discarded by epilogue guard)
    const int ar0 = (row0 + trow0 < N) ? row0 + trow0 : N - 1;
    const int ar1 = (row0 + trow1 < N) ? row0 + trow1 : N - 1;
    const size_t aoff0 = (size_t)ar0 * S + j * 8;
    const size_t aoff1 = (size_t)ar1 * S + j * 8;
    const size_t boff0 = (size_t)(col0 + trow0) * K + j * 8;
    const size_t boff1 = (size_t)(col0 + trow1) * K + j * 8;
    const int lds0 = (wave * 32) * 32;        // shorts; wave-uniform
    const int lds1 = (wave * 32 + 16) * 32;

    const int iters = K >> 5;

    // issue tile t's 4 DMAs (this wave's share) into slot s
    auto issue = [&](int t, int s) {
        const int k0 = t << 5;
        const unsigned short* Ab = (k0 < K0) ? (A0 + k0) : (A1 + (k0 - K0));
        const unsigned short* Wb = W + k0;
        GLOAD_LDS16(Ab + aoff0, &As[s][lds0]);
        GLOAD_LDS16(Ab + aoff1, &As[s][lds1]);
        GLOAD_LDS16(Wb + boff0, &Bs[s][lds0]);
        GLOAD_LDS16(Wb + boff1, &Bs[s][lds1]);
    };

    f32x4 acc[4][4];
    #pragma unroll
    for (int mt = 0; mt < 4; ++mt)
        #pragma unroll
        for (int nt = 0; nt < 4; ++nt)
            acc[mt][nt] = (f32x4){0.f, 0.f, 0.f, 0.f};

    // prologue: depth-2 prefetch (8 loads outstanding per wave)
    issue(0, 0);
    issue(1, 1);

    for (int i = 0; i < iters; ++i) {
        int t = i + 2;
        if (t > iters - 1) t = iters - 1;   // uniform tail re-issue
        issue(t, (i + 2) & 3);              // 12 outstanding
        __builtin_amdgcn_s_waitcnt(WAITCNT_VM8);   // my tile-i loads done
        asm volatile("s_barrier" ::: "memory");    // all waves' tile-i done

        const int cur = i & 3;
        bf16x8 af[4], bfr[4];
        #pragma unroll
        for (int mt = 0; mt < 4; ++mt)
            af[mt] = *(const bf16x8*)&As[cur][(wm * 64 + mt * 16 + cl) * 32 + quad * 8];
        #pragma unroll
        for (int nt = 0; nt < 4; ++nt)
            bfr[nt] = *(const bf16x8*)&Bs[cur][(wn * 64 + nt * 16 + cl) * 32 + quad * 8];

        #pragma unroll
        for (int mt = 0; mt < 4; ++mt)
            #pragma unroll
            for (int nt = 0; nt < 4; ++nt)
                acc[mt][nt] = __builtin_amdgcn_mfma_f32_16x16x32_bf16(
                    af[mt], bfr[nt], acc[mt][nt], 0, 0, 0);
    }

    if (mode == 0) {
        #pragma unroll
        for (int nt = 0; nt < 4; ++nt) {
            const int colx = col0 + wn * 64 + nt * 16 + cl;
            const float bb = b[colx];
            #pragma unroll
            for (int mt = 0; mt < 4; ++mt) {
                #pragma unroll
                for (int rr = 0; rr < 4; ++rr) {
                    int row = row0 + wm * 64 + mt * 16 + quad * 4 + rr;
                    if (row < N)
                        outb[(size_t)row * C + colx] =
                            (unsigned short)f2bf(fmaxf(acc[mt][nt][rr] + bb, 0.0f));
                }
            }
        }
    } else {
        float bv[4], wv2[4];
        #pragma unroll
        for (int nt = 0; nt < 4; ++nt) {
            const int colx = col0 + wn * 64 + nt * 16 + cl;
            bv[nt] = b[colx];
            wv2[nt] = Wo[colx];
        }
        #pragma unroll
        for (int mt = 0; mt < 4; ++mt) {
            #pragma unroll
            for (int rr = 0; rr < 4; ++rr) {
                float s = 0.0f;
                #pragma unroll
                for (int nt = 0; nt < 4; ++nt)
                    s += fmaxf(acc[mt][nt][rr] + bv[nt], 0.0f) * wv2[nt];
                s += __shfl_xor(s, 1);
                s += __shfl_xor(s, 2);
                s += __shfl_xor(s, 4);
                s += __shfl_xor(s, 8);
                int row = row0 + wm * 64 + mt * 16 + quad * 4 + rr;
                if (cl == 0 && row < N) atomicAdd(&logit[row], s);
            }
        }
    }
}

__global__ void head_kernel(const float* __restrict__ logit, const float* __restrict__ bo,
                            float* __restrict__ out, int N) {
    int i = blockIdx.x * 256 + threadIdx.x;
    if (i < N) out[i] = 1.0f / (1.0f + expf(-(logit[i] + bo[0])));
}

extern "C" void kernel_launch(void* const* d_in, const int* in_sizes, int n_in,
                              void* d_out, int out_size, void* d_ws, size_t ws_size,
                              hipStream_t stream) {
    const float* x  = (const float*)d_in[0];
    const int*   ei = (const int*)d_in[1];
    const float* W1 = (const float*)d_in[2];
    const float* b1 = (const float*)d_in[3];
    const float* W2 = (const float*)d_in[4];
    const float* b2 = (const float*)d_in[5];
    const float* Wo = (const float*)d_in[6];
    const float* bo = (const float*)d_in[7];
    float* out = (float*)d_out;

    const int N = in_sizes[0] / 128;   // 50000
    const int E = in_sizes[1] / 2;     // 400000
    const int* src = ei;
    const int* dst = ei + E;

    char* ws = (char*)d_ws;
    size_t off = 0;
    auto alloc = [&](size_t bytes) {
        void* p = ws + off;
        off += (bytes + 255) & ~(size_t)255;
        return p;
    };
    int* deg      = (int*)alloc((size_t)N * 4);
    int* rowstart = (int*)alloc((size_t)(N + 1) * 4);
    int* cursor   = (int*)alloc((size_t)N * 4);
    int* partial  = (int*)alloc((size_t)64 * 4);
    int* ebuf     = (int*)alloc((size_t)E * 4);
    float* logit  = (float*)alloc((size_t)N * 4);
    unsigned short* xb  = (unsigned short*)alloc((size_t)N * 128 * 2);
    unsigned short* W1b = (unsigned short*)alloc((size_t)512 * 256 * 2);
    unsigned short* W2b = (unsigned short*)alloc((size_t)512 * 1024 * 2);
    unsigned short* n1b = (unsigned short*)alloc((size_t)N * 128 * 2);
    unsigned short* h1b = (unsigned short*)alloc((size_t)N * 512 * 2);
    unsigned short* n2b = (unsigned short*)alloc((size_t)N * 512 * 2);
    (void)ws_size; (void)n_in; (void)out_size;

    hipMemsetAsync(deg,   0, (size_t)N * 4, stream);
    hipMemsetAsync(logit, 0, (size_t)N * 4, stream);

    // fused: cvt x/W1/W2 -> bf16  +  deg histogram (independent DAG roots)
    const int na4 = N * 128 / 4, nb4 = 512 * 256 / 4, nc4 = 512 * 1024 / 4;
    const int cvt_blocks  = ceil_div(na4 + nb4 + nc4, 256);
    const int hist_blocks = ceil_div(E, 256);
    cvt3_hist_kernel<<<cvt_blocks + hist_blocks, 256, 0, stream>>>(
        x, xb, na4, W1, W1b, nb4, W2, W2b, nc4, dst, deg, E, cvt_blocks);

    // CSR build (hierarchical scan)
    const int P = ceil_div(N, 1024);   // 49
    chunk_reduce<<<P, 256, 0, stream>>>(deg, partial, N);
    partial_scan<<<1, 64, 0, stream>>>(partial, rowstart + N, P);
    chunk_scan<<<P, 256, 0, stream>>>(deg, partial, rowstart, cursor, N);
    bucket_kernel<<<ceil_div(E, 256), 256, 0, stream>>>(src, dst, cursor, ebuf, E);

    // XCD-swizzled 1D grid: rows padded to x8, 4 col tiles, 8 xcd slots
    const int nrow = ceil_div(N, 128);              // 391
    const int gblocks = ceil_div(nrow, 8) * 8 * 4;  // 1568

    // layer 1
    gather_mean_128<<<ceil_div(N * 64, 256), 256, 0, stream>>>(rowstart, ebuf,
                                                               (const unsigned*)xb, (unsigned*)n1b, N);
    gemm_mfma<<<gblocks, 256, 0, stream>>>(xb, n1b, W1b, b1, h1b, nullptr, nullptr,
                                           N, 128, 128, 512, 0);

    // layer 2 + fused head
    gather_mean_512<<<ceil_div(N * 64, 256), 256, 0, stream>>>(rowstart, ebuf, h1b, n2b, N);
    gemm_mfma<<<gblocks, 256, 0, stream>>>(h1b, n2b, W2b, b2, nullptr, Wo, logit,
                                           N, 512, 512, 512, 1);

    head_kernel<<<ceil_div(N, 256), 256, 0, stream>>>(logit, bo, out, N);
}

// Round 16
// 351.328 us; speedup vs baseline: 1.0580x; 1.0580x over previous
//
#include <hip/hip_runtime.h>
#include <math.h>

// ---------------------------------------------------------------------------
// GraphSAGE fraud detector. CSR-gather aggregation + bf16 MFMA GEMMs.
// R16 = R14-exact revert (352 us, best). R15's manual-waitcnt pipeline
// (4 slots, vmcnt(8), raw s_barrier) regressed to 96 us/gemm: the 64 KB
// LDS cost 2 blocks/CU — same occupancy tax that killed R11/R13. The
// R12/R14 GEMM (BK=32, 32KB dbuf, XCD swizzle, 86 us) dominates every
// pipelining variant expressible at HIP level; the remaining ~20% barrier
// drain needs hipBLASLt-style hand-asm interleaving (s02/s10v2).
// MFMA 16x16x32 bf16: A-frag A[m=lane&15][k=quad*8+j]; C/D col=lane&15,
// row=quad*4+reg (m89/m97-verified layouts).
// ---------------------------------------------------------------------------

typedef __attribute__((ext_vector_type(8))) short bf16x8;   // 8 bf16, 4 VGPRs
typedef __attribute__((ext_vector_type(4))) float f32x4;

static inline int ceil_div(int a, int b) { return (a + b - 1) / b; }

__device__ inline float bf2f_lo(unsigned u) { return __builtin_bit_cast(float, u << 16); }
__device__ inline float bf2f_hi(unsigned u) { return __builtin_bit_cast(float, u & 0xffff0000u); }
__device__ inline unsigned f2bf(float f) {   // RNE round to bf16, bits in low 16
    unsigned u = __builtin_bit_cast(unsigned, f);
    u += 0x7fffu + ((u >> 16) & 1u);
    return u >> 16;
}

// async global->LDS, 16 B per lane; LDS dest = wave-uniform base + lane*16
#define GLOAD_LDS16(gp, lp)                                                   \
    __builtin_amdgcn_global_load_lds(                                         \
        (__attribute__((address_space(1))) void*)(gp),                        \
        (__attribute__((address_space(3))) void*)(lp), 16, 0, 0)

// ---------------- fused cvt(x,W1,W2) + deg histogram ----------------

__global__ void cvt3_hist_kernel(const float* __restrict__ a, unsigned short* __restrict__ ao, int na4,
                                 const float* __restrict__ b, unsigned short* __restrict__ bo, int nb4,
                                 const float* __restrict__ c, unsigned short* __restrict__ co, int nc4,
                                 const int* __restrict__ dst, int* __restrict__ deg, int E,
                                 int cvt_blocks) {
    if ((int)blockIdx.x < cvt_blocks) {
        int i = blockIdx.x * 256 + threadIdx.x;
        const float* in; unsigned short* out; int k;
        if (i < na4)                  { in = a; out = ao; k = i; }
        else if (i < na4 + nb4)       { in = b; out = bo; k = i - na4; }
        else if (i < na4 + nb4 + nc4) { in = c; out = co; k = i - na4 - nb4; }
        else return;
        float4 v = ((const float4*)in)[k];
        ushort4 o;
        o.x = (unsigned short)f2bf(v.x);
        o.y = (unsigned short)f2bf(v.y);
        o.z = (unsigned short)f2bf(v.z);
        o.w = (unsigned short)f2bf(v.w);
        ((ushort4*)out)[k] = o;
    } else {
        int e = (blockIdx.x - cvt_blocks) * 256 + threadIdx.x;
        if (e < E) atomicAdd(&deg[dst[e]], 1);
    }
}

// ---------------- CSR build ----------------

// per-1024-chunk sums
__global__ __launch_bounds__(256) void chunk_reduce(const int* __restrict__ deg,
                                                    int* __restrict__ partial, int N) {
    int base = blockIdx.x * 1024;
    int s = 0;
    for (int i = threadIdx.x; i < 1024; i += 256) {
        int idx = base + i;
        if (idx < N) s += deg[idx];
    }
    #pragma unroll
    for (int off = 32; off; off >>= 1) s += __shfl_down(s, off);
    __shared__ int ws[4];
    if ((threadIdx.x & 63) == 0) ws[threadIdx.x >> 6] = s;
    __syncthreads();
    if (threadIdx.x == 0) partial[blockIdx.x] = ws[0] + ws[1] + ws[2] + ws[3];
}

// exclusive scan of P<=64 partials (one wave); writes rowstart[N]=total
__global__ void partial_scan(int* __restrict__ partial, int* __restrict__ rowstartN, int P) {
    int lane = threadIdx.x;
    int v = (lane < P) ? partial[lane] : 0;
    int incl = v;
    #pragma unroll
    for (int off = 1; off < 64; off <<= 1) {
        int t = __shfl_up(incl, off);
        if (lane >= off) incl += t;
    }
    if (lane < P) partial[lane] = incl - v;
    if (lane == 63) *rowstartN = incl;
}

// per-chunk exclusive scan + global offset; writes rowstart and cursor
__global__ __launch_bounds__(256) void chunk_scan(const int* __restrict__ deg,
                                                  const int* __restrict__ partial,
                                                  int* __restrict__ rowstart,
                                                  int* __restrict__ cursor, int N) {
    int base = blockIdx.x * 1024 + threadIdx.x * 4;
    int v[4];
    #pragma unroll
    for (int j = 0; j < 4; ++j) {
        int i = base + j;
        v[j] = (i < N) ? deg[i] : 0;
    }
    int mysum = v[0] + v[1] + v[2] + v[3];
    int incl = mysum;
    int lane = threadIdx.x & 63, wave = threadIdx.x >> 6;
    #pragma unroll
    for (int off = 1; off < 64; off <<= 1) {
        int t = __shfl_up(incl, off);
        if (lane >= off) incl += t;
    }
    __shared__ int ws[4];
    if (lane == 63) ws[wave] = incl;
    __syncthreads();
    int run = partial[blockIdx.x] + incl - mysum;
    for (int w = 0; w < wave; ++w) run += ws[w];
    #pragma unroll
    for (int j = 0; j < 4; ++j) {
        int i = base + j;
        if (i < N) { rowstart[i] = run; cursor[i] = run; }
        run += v[j];
    }
}

__global__ void bucket_kernel(const int* __restrict__ src, const int* __restrict__ dst,
                              int* __restrict__ cursor, int* __restrict__ ebuf, int E) {
    int e = blockIdx.x * 256 + threadIdx.x;
    if (e < E) {
        int pos = atomicAdd(&cursor[dst[e]], 1);
        ebuf[pos] = src[e];
    }
}

// ---------------- gather means ----------------

// one wave per dst row; bf16 xb [N,128] -> bf16 mean [N,128]; fp32 accum
__global__ void gather_mean_128(const int* __restrict__ rowstart, const int* __restrict__ ebuf,
                                const unsigned* __restrict__ featb, unsigned* __restrict__ outb, int N) {
    int w = (blockIdx.x * blockDim.x + threadIdx.x) >> 6;
    int lane = threadIdx.x & 63;
    if (w >= N) return;
    int e0 = rowstart[w], e1 = rowstart[w + 1];
    float ax = 0.0f, ay = 0.0f;
    int i = e0;
    for (; i + 8 <= e1; i += 8) {           // 8-edge unroll for MLP
        unsigned v0 = featb[(size_t)ebuf[i]     * 64 + lane];
        unsigned v1 = featb[(size_t)ebuf[i + 1] * 64 + lane];
        unsigned v2 = featb[(size_t)ebuf[i + 2] * 64 + lane];
        unsigned v3 = featb[(size_t)ebuf[i + 3] * 64 + lane];
        unsigned v4 = featb[(size_t)ebuf[i + 4] * 64 + lane];
        unsigned v5 = featb[(size_t)ebuf[i + 5] * 64 + lane];
        unsigned v6 = featb[(size_t)ebuf[i + 6] * 64 + lane];
        unsigned v7 = featb[(size_t)ebuf[i + 7] * 64 + lane];
        ax += bf2f_lo(v0) + bf2f_lo(v1) + bf2f_lo(v2) + bf2f_lo(v3)
            + bf2f_lo(v4) + bf2f_lo(v5) + bf2f_lo(v6) + bf2f_lo(v7);
        ay += bf2f_hi(v0) + bf2f_hi(v1) + bf2f_hi(v2) + bf2f_hi(v3)
            + bf2f_hi(v4) + bf2f_hi(v5) + bf2f_hi(v6) + bf2f_hi(v7);
    }
    for (; i < e1; ++i) {
        unsigned v = featb[(size_t)ebuf[i] * 64 + lane];
        ax += bf2f_lo(v); ay += bf2f_hi(v);
    }
    float inv = 1.0f / fmaxf((float)(e1 - e0), 1.0f);
    outb[(size_t)w * 64 + lane] = f2bf(ax * inv) | (f2bf(ay * inv) << 16);
}

// one wave per dst row; bf16 feat [N,512] -> bf16 mean [N,512]; fp32 accum
__global__ void gather_mean_512(const int* __restrict__ rowstart, const int* __restrict__ ebuf,
                                const unsigned short* __restrict__ featb,
                                unsigned short* __restrict__ outb, int N) {
    int w = (blockIdx.x * blockDim.x + threadIdx.x) >> 6;
    int lane = threadIdx.x & 63;
    if (w >= N) return;
    int e0 = rowstart[w], e1 = rowstart[w + 1];
    float a[8] = {0, 0, 0, 0, 0, 0, 0, 0};
    const uint4* base = (const uint4*)featb;     // 512 bf16/row = 64 uint4/row
    int i = e0;
    for (; i + 8 <= e1; i += 8) {           // 8-edge unroll for MLP
        uint4 v0 = base[(size_t)ebuf[i]     * 64 + lane];
        uint4 v1 = base[(size_t)ebuf[i + 1] * 64 + lane];
        uint4 v2 = base[(size_t)ebuf[i + 2] * 64 + lane];
        uint4 v3 = base[(size_t)ebuf[i + 3] * 64 + lane];
        uint4 v4 = base[(size_t)ebuf[i + 4] * 64 + lane];
        uint4 v5 = base[(size_t)ebuf[i + 5] * 64 + lane];
        uint4 v6 = base[(size_t)ebuf[i + 6] * 64 + lane];
        uint4 v7 = base[(size_t)ebuf[i + 7] * 64 + lane];
        a[0] += bf2f_lo(v0.x) + bf2f_lo(v1.x) + bf2f_lo(v2.x) + bf2f_lo(v3.x)
              + bf2f_lo(v4.x) + bf2f_lo(v5.x) + bf2f_lo(v6.x) + bf2f_lo(v7.x);
        a[1] += bf2f_hi(v0.x) + bf2f_hi(v1.x) + bf2f_hi(v2.x) + bf2f_hi(v3.x)
              + bf2f_hi(v4.x) + bf2f_hi(v5.x) + bf2f_hi(v6.x) + bf2f_hi(v7.x);
        a[2] += bf2f_lo(v0.y) + bf2f_lo(v1.y) + bf2f_lo(v2.y) + bf2f_lo(v3.y)
              + bf2f_lo(v4.y) + bf2f_lo(v5.y) + bf2f_lo(v6.y) + bf2f_lo(v7.y);
        a[3] += bf2f_hi(v0.y) + bf2f_hi(v1.y) + bf2f_hi(v2.y) + bf2f_hi(v3.y)
              + bf2f_hi(v4.y) + bf2f_hi(v5.y) + bf2f_hi(v6.y) + bf2f_hi(v7.y);
        a[4] += bf2f_lo(v0.z) + bf2f_lo(v1.z) + bf2f_lo(v2.z) + bf2f_lo(v3.z)
              + bf2f_lo(v4.z) + bf2f_lo(v5.z) + bf2f_lo(v6.z) + bf2f_lo(v7.z);
        a[5] += bf2f_hi(v0.z) + bf2f_hi(v1.z) + bf2f_hi(v2.z) + bf2f_hi(v3.z)
              + bf2f_hi(v4.z) + bf2f_hi(v5.z) + bf2f_hi(v6.z) + bf2f_hi(v7.z);
        a[6] += bf2f_lo(v0.w) + bf2f_lo(v1.w) + bf2f_lo(v2.w) + bf2f_lo(v3.w)
              + bf2f_lo(v4.w) + bf2f_lo(v5.w) + bf2f_lo(v6.w) + bf2f_lo(v7.w);
        a[7] += bf2f_hi(v0.w) + bf2f_hi(v1.w) + bf2f_hi(v2.w) + bf2f_hi(v3.w)
              + bf2f_hi(v4.w) + bf2f_hi(v5.w) + bf2f_hi(v6.w) + bf2f_hi(v7.w);
    }
    for (; i < e1; ++i) {
        uint4 v = base[(size_t)ebuf[i] * 64 + lane];
        a[0] += bf2f_lo(v.x); a[1] += bf2f_hi(v.x);
        a[2] += bf2f_lo(v.y); a[3] += bf2f_hi(v.y);
        a[4] += bf2f_lo(v.z); a[5] += bf2f_hi(v.z);
        a[6] += bf2f_lo(v.w); a[7] += bf2f_hi(v.w);
    }
    float inv = 1.0f / fmaxf((float)(e1 - e0), 1.0f);
    uint4 o;
    o.x = f2bf(a[0] * inv) | (f2bf(a[1] * inv) << 16);
    o.y = f2bf(a[2] * inv) | (f2bf(a[3] * inv) << 16);
    o.z = f2bf(a[4] * inv) | (f2bf(a[5] * inv) << 16);
    o.w = f2bf(a[6] * inv) | (f2bf(a[7] * inv) << 16);
    ((uint4*)outb)[(size_t)w * 64 + lane] = o;
}

// ---------------- bf16 MFMA GEMM (R12-exact: BK=32, XCD swizzle) -----------
// C = relu([A0b | A1b] @ Wb^T + b)
// mode 0: store C as bf16 to outb [N, C]
// mode 1: logit[row] += sum_col C[row,col] * Wo[col]
// 1D grid, id -> xcd=id&7, col=(id>>3)&3, row=(id>>5)*8+xcd: the 4 column
// siblings of each A row-tile run on ONE XCD -> A L2-resident, fetched once.
// Block 256 thr = 4 waves (2x2); tile 128x128; wave tile 64x64 (4x4 mfma);
// BK=32, double-buffered LDS, one barrier per iter.
// Staging: lane = 4r+j loads row (wave*32 [+16] + r)'s j-th 16B of its 64B
// K-slice -> 16 contiguous 64B segments per wave-instruction.
// LDS per buffer: row-major [128][32] bf16 tile (8 KB).
// REQUIRES K0 == K1 (multiples of 32), C == 512.
__global__ __launch_bounds__(256) void gemm_mfma(
    const unsigned short* __restrict__ A0,   // [N, K0] bf16
    const unsigned short* __restrict__ A1,   // [N, K1] bf16, K1 == K0
    const unsigned short* __restrict__ W,    // [C, K0+K1] bf16 row-major
    const float* __restrict__ b,             // [C] fp32
    unsigned short* __restrict__ outb,       // [N, C] bf16 (mode 0)
    const float* __restrict__ Wo,            // [C] fp32    (mode 1)
    float* __restrict__ logit,               // [N] fp32    (mode 1)
    int N, int K0, int K1, int C, int mode)
{
    // --- XCD-aware decode ---
    const int nrow = (N + 127) >> 7;
    const int id   = blockIdx.x;
    const int rowb = ((id >> 5) << 3) + (id & 7);   // rslot*8 + xcd
    const int colb = (id >> 3) & 3;
    if (rowb >= nrow) return;

    const int K = K0 + K1;
    const int S = K0;               // row stride of both A0 and A1
    __shared__ short As[2][4096];   // [128][32] per buffer, 8 KB
    __shared__ short Bs[2][4096];

    const int tid  = threadIdx.x;
    const int lane = tid & 63;
    const int wave = tid >> 6;
    const int wm = wave & 1, wn = wave >> 1;
    const int cl = lane & 15, quad = lane >> 4;
    const int row0 = rowb * 128;
    const int col0 = colb * 128;

    // staging: lane = 4r+j; wave w, load i covers tile rows w*32+i*16 .. +16
    const int r = lane >> 2;        // 0..15
    const int j = lane & 3;         // 16B chunk within the row's 64B K-slice
    const int trow0 = wave * 32 + r;
    const int trow1 = trow0 + 16;
    // clamp OOB tile rows to N-1 (loaded garbage discarded by epilogue guard)
    const int ar0 = (row0 + trow0 < N) ? row0 + trow0 : N - 1;
    const int ar1 = (row0 + trow1 < N) ? row0 + trow1 : N - 1;
    const size_t aoff0 = (size_t)ar0 * S + j * 8;
    const size_t aoff1 = (size_t)ar1 * S + j * 8;
    const size_t boff0 = (size_t)(col0 + trow0) * K + j * 8;
    const size_t boff1 = (size_t)(col0 + trow1) * K + j * 8;
    const int lds0 = (wave * 32) * 32;        // shorts; wave-uniform
    const int lds1 = (wave * 32 + 16) * 32;

    f32x4 acc[4][4];
    #pragma unroll
    for (int mt = 0; mt < 4; ++mt)
        #pragma unroll
        for (int nt = 0; nt < 4; ++nt)
            acc[mt][nt] = (f32x4){0.f, 0.f, 0.f, 0.f};

    // prologue: DMA tile 0 into buffer 0
    GLOAD_LDS16(A0 + aoff0, &As[0][lds0]);
    GLOAD_LDS16(A0 + aoff1, &As[0][lds1]);
    GLOAD_LDS16(W  + boff0, &Bs[0][lds0]);
    GLOAD_LDS16(W  + boff1, &Bs[0][lds1]);

    const int iters = K >> 5;
    for (int i = 0; i < iters; ++i) {
        const int cur = i & 1;
        // barrier drains tile i's DMA (vmcnt0) and fences tile i-1 frag reads
        __syncthreads();
        if (i + 1 < iters) {
            const int kn = (i + 1) << 5;
            const unsigned short* Ab = (kn < K0) ? (A0 + kn) : (A1 + (kn - K0));
            const unsigned short* Wb = W + kn;
            const int nb = cur ^ 1;
            GLOAD_LDS16(Ab + aoff0, &As[nb][lds0]);
            GLOAD_LDS16(Ab + aoff1, &As[nb][lds1]);
            GLOAD_LDS16(Wb + boff0, &Bs[nb][lds0]);
            GLOAD_LDS16(Wb + boff1, &Bs[nb][lds1]);
        }

        bf16x8 af[4], bfr[4];
        #pragma unroll
        for (int mt = 0; mt < 4; ++mt)
            af[mt] = *(const bf16x8*)&As[cur][(wm * 64 + mt * 16 + cl) * 32 + quad * 8];
        #pragma unroll
        for (int nt = 0; nt < 4; ++nt)
            bfr[nt] = *(const bf16x8*)&Bs[cur][(wn * 64 + nt * 16 + cl) * 32 + quad * 8];

        #pragma unroll
        for (int mt = 0; mt < 4; ++mt)
            #pragma unroll
            for (int nt = 0; nt < 4; ++nt)
                acc[mt][nt] = __builtin_amdgcn_mfma_f32_16x16x32_bf16(
                    af[mt], bfr[nt], acc[mt][nt], 0, 0, 0);
    }

    if (mode == 0) {
        #pragma unroll
        for (int nt = 0; nt < 4; ++nt) {
            const int colx = col0 + wn * 64 + nt * 16 + cl;
            const float bb = b[colx];
            #pragma unroll
            for (int mt = 0; mt < 4; ++mt) {
                #pragma unroll
                for (int rr = 0; rr < 4; ++rr) {
                    int row = row0 + wm * 64 + mt * 16 + quad * 4 + rr;
                    if (row < N)
                        outb[(size_t)row * C + colx] =
                            (unsigned short)f2bf(fmaxf(acc[mt][nt][rr] + bb, 0.0f));
                }
            }
        }
    } else {
        float bv[4], wv2[4];
        #pragma unroll
        for (int nt = 0; nt < 4; ++nt) {
            const int colx = col0 + wn * 64 + nt * 16 + cl;
            bv[nt] = b[colx];
            wv2[nt] = Wo[colx];
        }
        #pragma unroll
        for (int mt = 0; mt < 4; ++mt) {
            #pragma unroll
            for (int rr = 0; rr < 4; ++rr) {
                float s = 0.0f;
                #pragma unroll
                for (int nt = 0; nt < 4; ++nt)
                    s += fmaxf(acc[mt][nt][rr] + bv[nt], 0.0f) * wv2[nt];
                s += __shfl_xor(s, 1);
                s += __shfl_xor(s, 2);
                s += __shfl_xor(s, 4);
                s += __shfl_xor(s, 8);
                int row = row0 + wm * 64 + mt * 16 + quad * 4 + rr;
                if (cl == 0 && row < N) atomicAdd(&logit[row], s);
            }
        }
    }
}

__global__ void head_kernel(const float* __restrict__ logit, const float* __restrict__ bo,
                            float* __restrict__ out, int N) {
    int i = blockIdx.x * 256 + threadIdx.x;
    if (i < N) out[i] = 1.0f / (1.0f + expf(-(logit[i] + bo[0])));
}

extern "C" void kernel_launch(void* const* d_in, const int* in_sizes, int n_in,
                              void* d_out, int out_size, void* d_ws, size_t ws_size,
                              hipStream_t stream) {
    const float* x  = (const float*)d_in[0];
    const int*   ei = (const int*)d_in[1];
    const float* W1 = (const float*)d_in[2];
    const float* b1 = (const float*)d_in[3];
    const float* W2 = (const float*)d_in[4];
    const float* b2 = (const float*)d_in[5];
    const float* Wo = (const float*)d_in[6];
    const float* bo = (const float*)d_in[7];
    float* out = (float*)d_out;

    const int N = in_sizes[0] / 128;   // 50000
    const int E = in_sizes[1] / 2;     // 400000
    const int* src = ei;
    const int* dst = ei + E;

    char* ws = (char*)d_ws;
    size_t off = 0;
    auto alloc = [&](size_t bytes) {
        void* p = ws + off;
        off += (bytes + 255) & ~(size_t)255;
        return p;
    };
    int* deg      = (int*)alloc((size_t)N * 4);
    int* rowstart = (int*)alloc((size_t)(N + 1) * 4);
    int* cursor   = (int*)alloc((size_t)N * 4);
    int* partial  = (int*)alloc((size_t)64 * 4);
    int* ebuf     = (int*)alloc((size_t)E * 4);
    float* logit  = (float*)alloc((size_t)N * 4);
    unsigned short* xb  = (unsigned short*)alloc((size_t)N * 128 * 2);
    unsigned short* W1b = (unsigned short*)alloc((size_t)512 * 256 * 2);
    unsigned short* W2b = (unsigned short*)alloc((size_t)512 * 1024 * 2);
    unsigned short* n1b = (unsigned short*)alloc((size_t)N * 128 * 2);
    unsigned short* h1b = (unsigned short*)alloc((size_t)N * 512 * 2);
    unsigned short* n2b = (unsigned short*)alloc((size_t)N * 512 * 2);
    (void)ws_size; (void)n_in; (void)out_size;

    hipMemsetAsync(deg,   0, (size_t)N * 4, stream);
    hipMemsetAsync(logit, 0, (size_t)N * 4, stream);

    // fused: cvt x/W1/W2 -> bf16  +  deg histogram (independent DAG roots)
    const int na4 = N * 128 / 4, nb4 = 512 * 256 / 4, nc4 = 512 * 1024 / 4;
    const int cvt_blocks  = ceil_div(na4 + nb4 + nc4, 256);
    const int hist_blocks = ceil_div(E, 256);
    cvt3_hist_kernel<<<cvt_blocks + hist_blocks, 256, 0, stream>>>(
        x, xb, na4, W1, W1b, nb4, W2, W2b, nc4, dst, deg, E, cvt_blocks);

    // CSR build (hierarchical scan)
    const int P = ceil_div(N, 1024);   // 49
    chunk_reduce<<<P, 256, 0, stream>>>(deg, partial, N);
    partial_scan<<<1, 64, 0, stream>>>(partial, rowstart + N, P);
    chunk_scan<<<P, 256, 0, stream>>>(deg, partial, rowstart, cursor, N);
    bucket_kernel<<<ceil_div(E, 256), 256, 0, stream>>>(src, dst, cursor, ebuf, E);

    // XCD-swizzled 1D grid: rows padded to x8, 4 col tiles, 8 xcd slots
    const int nrow = ceil_div(N, 128);              // 391
    const int gblocks = ceil_div(nrow, 8) * 8 * 4;  // 1568

    // layer 1
    gather_mean_128<<<ceil_div(N * 64, 256), 256, 0, stream>>>(rowstart, ebuf,
                                                               (const unsigned*)xb, (unsigned*)n1b, N);
    gemm_mfma<<<gblocks, 256, 0, stream>>>(xb, n1b, W1b, b1, h1b, nullptr, nullptr,
                                           N, 128, 128, 512, 0);

    // layer 2 + fused head
    gather_mean_512<<<ceil_div(N * 64, 256), 256, 0, stream>>>(rowstart, ebuf, h1b, n2b, N);
    gemm_mfma<<<gblocks, 256, 0, stream>>>(h1b, n2b, W2b, b2, nullptr, Wo, logit,
                                           N, 512, 512, 512, 1);

    head_kernel<<<ceil_div(N, 256), 256, 0, stream>>>(logit, bo, out, N);
}